// Round 13
// baseline (61.719 us; speedup 1.0000x reference)
//
#include <hip/hip_runtime.h>
#include <hip/hip_bf16.h>

// Problem dims (fixed by reference)
#define BB 8
#define NN 96
#define DD 512
#define EE 4
#define ROWS 768

typedef __attribute__((ext_vector_type(8))) short s8v;   // 8 bf16 = 4 VGPRs
typedef __attribute__((ext_vector_type(4))) short s4v;
typedef __attribute__((ext_vector_type(4))) float f32x4;

// ---------------- ws layout (flat; ws = 256 MiB) ----------------
#define WS_PROJP   4096                 // f32 [8][6144]       = 196,608
#define WS_NODESH  1048576              // bf16 [768][512]     = 786,432
#define WS_ALLMSGS 2097152              // bf16 [8*768][512]   = 6,291,456
#define WS_ACAT    8388608              // bf16 [768][1536]    = 2,359,296
#define WS_EDGEST  10747904             // bf16 [8][512][512]  = 4,194,304
#define WS_WT      14942208             // bf16 [3][512][1536] = 4,718,592
#define WS_RN      19660800             // bf16 [768][512]     = 786,432
#define WS_ZB      20447232             // f32  [768][512]     = 1,572,864
#define WS_HPRE    22020096             // f32  [768][512]     = 1,572,864

__device__ __forceinline__ short f2bf(float x) {   // RNE f32->bf16
  unsigned int u = __builtin_bit_cast(unsigned int, x);
  u += 0x7FFFu + ((u >> 16) & 1u);
  return (short)(u >> 16);
}
__device__ __forceinline__ float b2f(short s) {
  unsigned int u = ((unsigned int)(unsigned short)s) << 16;
  return __builtin_bit_cast(float, u);
}

__device__ __forceinline__ f32x4 mfma16(s8v a, s8v b, f32x4 c) {
  asm("v_mfma_f32_16x16x32_bf16 %0, %1, %2, %0" : "+v"(c) : "v"(a), "v"(b));
  return c;
}

__device__ __forceinline__ int get_exist(const void* p, int code, int idx) {
  switch (code) {
    case 0: return ((const unsigned char*)p)[idx] != 0;
    case 1: return ((const int*)p)[idx] != 0;
    case 2: return ((const float*)p)[idx] != 0.0f;
    default: return ((const long long*)p)[idx] != 0;
  }
}

// ---------------- prep: flat 1D grid, 1102 blocks, 64x64 transpose tiles (R12) ----------------
__global__ __launch_bounds__(256) void k_prep(const float* __restrict__ edges,
                                              const float* __restrict__ Wr,
                                              const float* __restrict__ Wz,
                                              const float* __restrict__ Wh,
                                              const float* __restrict__ nodes,
                                              const void* exist_in,
                                              const void* exist_out,
                                              short* __restrict__ edgesT,
                                              short* __restrict__ WT,
                                              short* __restrict__ nodesH,
                                              short* __restrict__ AcatH,
                                              int* __restrict__ flags) {
  __shared__ float t[64][65];
  __shared__ int red[3];
  int task = blockIdx.x;
  int tt = threadIdx.x;
  if (task < 1088) {
    const float* src;
    short* dst;
    int dstPitch, r0, c0;
    if (task < 512) {
      int e = task >> 6, rem = task & 63;
      src = edges + (size_t)e * DD * DD;
      dst = edgesT + (size_t)e * DD * DD;
      dstPitch = DD;
      r0 = (rem >> 3) * 64; c0 = (rem & 7) * 64;
    } else {
      int q = task - 512;
      int z = q / 192, rem = q % 192;
      src = z == 0 ? Wr : (z == 1 ? Wz : Wh);
      dst = WT + (size_t)z * (512 * 1536);
      dstPitch = 1536;
      r0 = (rem >> 3) * 64; c0 = (rem & 7) * 64;
    }
    int row = tt >> 2, c16 = (tt & 3) * 16;
    const float* sp = src + (size_t)(r0 + row) * DD + c0 + c16;
#pragma unroll
    for (int i = 0; i < 4; ++i) {
      float4 v = *(const float4*)(sp + i * 4);
      t[row][c16 + i * 4 + 0] = v.x; t[row][c16 + i * 4 + 1] = v.y;
      t[row][c16 + i * 4 + 2] = v.z; t[row][c16 + i * 4 + 3] = v.w;
    }
    __syncthreads();
    short* dp = dst + (size_t)(c0 + row) * dstPitch + r0 + c16;
#pragma unroll
    for (int i = 0; i < 4; ++i) {
      s4v o;
      o[0] = f2bf(t[c16 + i * 4 + 0][row]);
      o[1] = f2bf(t[c16 + i * 4 + 1][row]);
      o[2] = f2bf(t[c16 + i * 4 + 2][row]);
      o[3] = f2bf(t[c16 + i * 4 + 3][row]);
      *(s4v*)(dp + i * 4) = o;
    }
  } else if (task < 1100) {
    int r0 = (task - 1088) * 64;
    int c4 = (tt & 127) * 4;
#pragma unroll 4
    for (int p2 = 0; p2 < 32; ++p2) {
      int row = r0 + p2 * 2 + (tt >> 7);
      float4 v = *(const float4*)(nodes + (size_t)row * DD + c4);
      s4v o;
      o[0] = f2bf(v.x); o[1] = f2bf(v.y); o[2] = f2bf(v.z); o[3] = f2bf(v.w);
      *(s4v*)(nodesH + (size_t)row * DD + c4) = o;
      *(s4v*)(AcatH + (size_t)row * 1536 + 1024 + c4) = o;
    }
  } else {
    int y = task - 1100;
    if (tt < 3) red[tt] = 0;
    __syncthreads();
    const uint4* p = (const uint4*)(y ? exist_out : exist_in);
    int mis = 0, gt = 0, od = 0;
    for (int i = tt; i < 4608; i += 256) {    // first 73728 bytes
      uint4 v = p[i];
      unsigned any = v.x | v.y | v.z | v.w;
      if (any) {
        if (any & 0xFFFFFF00u) mis = 1;
        if (any & 0xFEFEFEFEu) gt = 1;
        if (v.y | v.w) od = 1;
      }
    }
    if (mis) atomicOr(&red[0], 1);
    if (gt) atomicOr(&red[1], 1);
    if (od) atomicOr(&red[2], 1);
    __syncthreads();
    if (tt == 0) flags[y] = red[0] ? (red[1] ? 2 : 0) : (red[2] ? 1 : 3);
  }
}

// ---------------- MFMA tile helper (R6/R9 proven) ----------------
__device__ __forceinline__ void mfma_tile(const short* As, const short* Bs,
                                          int wr, int wc, int l, f32x4 acc[2][2]) {
  int lr = l & 15, lg = l >> 4;
#pragma unroll
  for (int ks = 0; ks < 64; ks += 32) {
    s8v a0 = *(const s8v*)&As[(wr + lr) * 72 + ks + 8 * lg];
    s8v a1 = *(const s8v*)&As[(wr + 16 + lr) * 72 + ks + 8 * lg];
    s8v b0 = *(const s8v*)&Bs[(wc + lr) * 72 + ks + 8 * lg];
    s8v b1 = *(const s8v*)&Bs[(wc + 16 + lr) * 72 + ks + 8 * lg];
    acc[0][0] = mfma16(a0, b0, acc[0][0]);
    acc[0][1] = mfma16(a0, b1, acc[0][1]);
    acc[1][0] = mfma16(a1, b0, acc[1][0]);
    acc[1][1] = mfma16(a1, b1, acc[1][1]);
  }
}

// ---------------- GEMM msgs (pipelined, R9 proven) + fused proj partials ----------------
__global__ __launch_bounds__(256) void k_gemm_msgs(const short* __restrict__ nodesH,
                                                   const short* __restrict__ edgesT,
                                                   const float* __restrict__ Wa_in,
                                                   const float* __restrict__ Wa_out,
                                                   short* __restrict__ C,
                                                   float* __restrict__ projp) {
  __shared__ __align__(16) short As[64 * 72];
  __shared__ __align__(16) short Bs[64 * 72];
  __shared__ float pp[128];
  int tid = threadIdx.x;
  int row0 = blockIdx.y * 64;
  int col0 = blockIdx.x * 64;        // [0,4096)
  int de = col0 >> 9, h0 = col0 & 511;
  int w = tid >> 6, l = tid & 63;
  int wr = (w >> 1) * 32, wc = (w & 1) * 32;
  int srow = tid >> 2, scc = (tid & 3) * 16;
  const short* Ap = nodesH + (size_t)(row0 + srow) * DD + scc;
  const short* Bp = edgesT + (size_t)de * DD * DD + (size_t)(h0 + srow) * DD + scc;
  s8v a0 = *(const s8v*)Ap, a1 = *(const s8v*)(Ap + 8);
  s8v b0 = *(const s8v*)Bp, b1 = *(const s8v*)(Bp + 8);
  f32x4 acc[2][2] = {};
  for (int k0 = 0; k0 < DD; k0 += 64) {
    *(s8v*)&As[srow * 72 + scc] = a0; *(s8v*)&As[srow * 72 + scc + 8] = a1;
    *(s8v*)&Bs[srow * 72 + scc] = b0; *(s8v*)&Bs[srow * 72 + scc + 8] = b1;
    __syncthreads();
    if (k0 + 64 < DD) {        // prefetch next K-tile into regs (overlaps MFMA)
      Ap += 64; Bp += 64;
      a0 = *(const s8v*)Ap; a1 = *(const s8v*)(Ap + 8);
      b0 = *(const s8v*)Bp; b1 = *(const s8v*)(Bp + 8);
    }
    mfma_tile(As, Bs, wr, wc, l, acc);
    __syncthreads();
  }
  asm volatile("s_nop 7\n\ts_nop 7");   // MFMA->VALU writeback hazard guard
  int lr = l & 15, lg4 = (l >> 4) * 4;
#pragma unroll
  for (int fi = 0; fi < 2; ++fi)
#pragma unroll
    for (int fj = 0; fj < 2; ++fj) {
      f32x4 v = acc[fi][fj];
#pragma unroll
      for (int r = 0; r < 4; ++r) {
        int row = row0 + wr + fi * 16 + lg4 + r;
        int col = h0 + wc + fj * 16 + lr;
        C[((size_t)(de * ROWS + row)) * DD + col] = f2bf(v[r]);
      }
    }
  // ---- fused proj partial ----
  const float* wa2 = ((de >> 2) ? Wa_out : Wa_in) + DD;
  float w0 = wa2[h0 + wc + lr];
  float w1 = wa2[h0 + wc + 16 + lr];
  float pr[2][4];
#pragma unroll
  for (int fi = 0; fi < 2; ++fi)
#pragma unroll
    for (int r = 0; r < 4; ++r)
      pr[fi][r] = acc[fi][0][r] * w0 + acc[fi][1][r] * w1;
#pragma unroll
  for (int off = 1; off < 16; off <<= 1)
#pragma unroll
    for (int fi = 0; fi < 2; ++fi)
#pragma unroll
      for (int r = 0; r < 4; ++r) pr[fi][r] += __shfl_xor(pr[fi][r], off);
  if (lr == 0) {
#pragma unroll
    for (int fi = 0; fi < 2; ++fi)
#pragma unroll
      for (int r = 0; r < 4; ++r)
        pp[(w & 1) * 64 + wr + fi * 16 + lg4 + r] = pr[fi][r];
  }
  __syncthreads();
  if (tid < 64)
    projp[(size_t)(blockIdx.x & 7) * 6144 + de * ROWS + row0 + tid] =
        pp[tid] + pp[64 + tid];
}

// ---------------- attention: compacted branchless gather (R9 proven) ----------------
__global__ __launch_bounds__(256) void k_attn(const short* __restrict__ allmsgsH,
                                              const float* __restrict__ projp,
                                              const int* __restrict__ adj_in,
                                              const int* __restrict__ adj_out,
                                              const void* exist_in,
                                              const void* exist_out,
                                              const int* __restrict__ fr,
                                              const float* __restrict__ nodes,
                                              const float* __restrict__ Wa_in,
                                              const float* __restrict__ ba_in,
                                              const float* __restrict__ Wa_out,
                                              const float* __restrict__ ba_out,
                                              short* __restrict__ AcatH) {
  __shared__ float s_w[NN];
  __shared__ int s_off[NN];
  __shared__ int s_list[NN];
  __shared__ int s_cnt[2];
  __shared__ float s_part[5];
  int blk = blockIdx.x;       // dir*768 + b*96 + i
  int dir = blk / ROWS;
  int row = blk % ROWS;
  int b = row / NN;
  const int* adj = dir ? adj_out : adj_in;
  const void* ex = dir ? exist_out : exist_in;
  int code = fr[dir];
  int t = threadIdx.x, wv = t >> 6, lane = t & 63;
  const float* wa = dir ? Wa_out : Wa_in;
  float2 nv = *(const float2*)(nodes + (size_t)row * DD + 2 * t);
  float p = fmaf(nv.x, wa[2 * t], nv.y * wa[2 * t + 1]);
#pragma unroll
  for (int off = 32; off; off >>= 1) p += __shfl_xor(p, off);
  if (lane == 0) s_part[wv] = p;
  int ex_ = 0, tj_ = 0;
  if (t < NN) {
    int idx = row * NN + t;
    ex_ = get_exist(ex, code, idx);
    tj_ = adj[idx];
    s_off[t] = ((dir * 4 + tj_) * ROWS + b * NN + t) * DD;
  }
  if (wv == 0) {
    unsigned long long m = __ballot(ex_);
    int pos = __popcll(m & ((1ull << lane) - 1));
    if (ex_) s_list[pos] = t;
    if (lane == 0) s_cnt[0] = (int)__popcll(m);
  } else if (wv == 1) {
    unsigned long long m = __ballot(t < NN && ex_);
    int pos = __popcll(m & ((1ull << lane) - 1));
    if (t < NN && ex_) s_list[64 + pos] = t;
    if (lane == 0) s_cnt[1] = (int)__popcll(m);
  }
  __syncthreads();
  float s1v = s_part[0] + s_part[1] + s_part[2] + s_part[3] +
              (dir ? ba_out[0] : ba_in[0]);
  if (t < NN) {
    float sc = -1e9f;
    if (ex_) {
      size_t base = (size_t)(dir * 4 + tj_) * ROWS + b * NN + t;
      float pv = 0.f;
#pragma unroll
      for (int c = 0; c < 8; ++c) pv += projp[(size_t)c * 6144 + base];
      float x = s1v + pv;
      sc = x >= 0.f ? x : 0.2f * x;
    }
    s_w[t] = sc;
  }
  __syncthreads();
  if (t < 64) {
    float e1 = s_w[t];
    float e2 = (t < 32) ? s_w[t + 64] : -1e30f;
    float mx = fmaxf(e1, e2);
#pragma unroll
    for (int off = 32; off; off >>= 1) mx = fmaxf(mx, __shfl_xor(mx, off));
    float w1 = (e1 > -1e8f) ? __expf(e1 - mx) : 0.f;
    float w2 = (t < 32 && e2 > -1e8f) ? __expf(e2 - mx) : 0.f;
    s_w[t] = w1;
    if (t < 32) s_w[t + 64] = w2;
    float sm = w1 + w2;
#pragma unroll
    for (int off = 32; off; off >>= 1) sm += __shfl_xor(sm, off);
    if (t == 0) s_part[4] = 1.f / sm;
  }
  __syncthreads();
  float inv = s_part[4];
  int c0 = s_cnt[0], c1 = s_cnt[1];
  float acc0 = 0.f, acc1 = 0.f;
  int t2 = 2 * t;
#pragma unroll 4
  for (int q = 0; q < c0; ++q) {
    int j = s_list[q];
    float wj = s_w[j];
    unsigned u = *(const unsigned*)(allmsgsH + s_off[j] + t2);
    acc0 = fmaf(wj, b2f((short)(u & 0xFFFF)), acc0);
    acc1 = fmaf(wj, b2f((short)(u >> 16)), acc1);
  }
#pragma unroll 4
  for (int q = 0; q < c1; ++q) {
    int j = s_list[64 + q];
    float wj = s_w[j];
    unsigned u = *(const unsigned*)(allmsgsH + s_off[j] + t2);
    acc0 = fmaf(wj, b2f((short)(u & 0xFFFF)), acc0);
    acc1 = fmaf(wj, b2f((short)(u >> 16)), acc1);
  }
  unsigned o0 = (unsigned short)f2bf(acc0 * inv);
  unsigned o1 = (unsigned short)f2bf(acc1 * inv);
  *(unsigned*)(AcatH + (size_t)row * 1536 + dir * DD + t2) = o0 | (o1 << 16);
}

// ---------------- GEMM1: 32x64 tiles, 2-wave blocks (tail fix) ----------------
__global__ __launch_bounds__(128) void k_gemm1(const short* __restrict__ AcatH,
                                               const short* __restrict__ WT,
                                               const float* __restrict__ br,
                                               const float* __restrict__ bz,
                                               const float* __restrict__ nodes,
                                               short* __restrict__ rnH,
                                               float* __restrict__ zb,
                                               float* __restrict__ Hpre) {
  __shared__ __align__(16) short As[32 * 72];
  __shared__ __align__(16) short Bs[64 * 72];
  int tid = threadIdx.x;
  int row0 = blockIdx.y * 32;           // [0,768)
  int col0 = blockIdx.x * 64;           // [0,1536)
  int region = col0 >> 9, c0 = col0 & 511;
  int K = (region == 2) ? 1024 : 1536;
  int w = tid >> 6, l = tid & 63;
  int wc = w * 32;                      // wave owns 32 rows x 32 cols, wr=0
  // A staging: 256 chunks of 16B, 2/thread: chunk c -> row c>>3, kc c&7
  int ac0 = tid * 2;
  int ar0 = ac0 >> 3, ak0 = (ac0 & 7) * 8;
  int ar1 = (ac0 + 1) >> 3, ak1 = ((ac0 + 1) & 7) * 8;
  // B staging: 512 chunks, 4/thread
  int bc0 = tid * 4;
  int br_ = bc0 >> 3, bk = (bc0 & 7) * 8;   // 4 consecutive chunks: same row (8 chunks/row, tid*4 aligned)
  const short* ApA = AcatH + (size_t)(row0 + ar0) * 1536 + ak0;
  const short* ApB = AcatH + (size_t)(row0 + ar1) * 1536 + ak1;
  const short* Bp = WT + (size_t)region * (512 * 1536) + (size_t)(c0 + br_) * 1536 + bk;
  s8v a0 = *(const s8v*)ApA, a1 = *(const s8v*)ApB;
  s8v b0 = *(const s8v*)Bp, b1 = *(const s8v*)(Bp + 8);
  s8v b2 = *(const s8v*)(Bp + 16), b3 = *(const s8v*)(Bp + 24);
  f32x4 acc[2][2] = {};
  for (int k0 = 0; k0 < K; k0 += 64) {
    *(s8v*)&As[ar0 * 72 + ak0] = a0;
    *(s8v*)&As[ar1 * 72 + ak1] = a1;
    *(s8v*)&Bs[br_ * 72 + bk] = b0;      *(s8v*)&Bs[br_ * 72 + bk + 8] = b1;
    *(s8v*)&Bs[br_ * 72 + bk + 16] = b2; *(s8v*)&Bs[br_ * 72 + bk + 24] = b3;
    __syncthreads();
    if (k0 + 64 < K) {
      ApA += 64; ApB += 64; Bp += 64;
      a0 = *(const s8v*)ApA; a1 = *(const s8v*)ApB;
      b0 = *(const s8v*)Bp; b1 = *(const s8v*)(Bp + 8);
      b2 = *(const s8v*)(Bp + 16); b3 = *(const s8v*)(Bp + 24);
    }
    mfma_tile(As, Bs, 0, wc, l, acc);
    __syncthreads();
  }
  asm volatile("s_nop 7\n\ts_nop 7");
  int lr = l & 15, lg4 = (l >> 4) * 4;
#pragma unroll
  for (int fi = 0; fi < 2; ++fi)
#pragma unroll
    for (int fj = 0; fj < 2; ++fj) {
      f32x4 v = acc[fi][fj];
#pragma unroll
      for (int r = 0; r < 4; ++r) {
        int row = row0 + fi * 16 + lg4 + r;
        int c = c0 + wc + fj * 16 + lr;
        float vv = v[r];
        size_t o = (size_t)row * DD + c;
        if (region == 0) {
          float s = 1.f / (1.f + __expf(-(vv + br[c])));
          rnH[o] = f2bf(s * nodes[o]);
        } else if (region == 1) {
          zb[o] = 1.f / (1.f + __expf(-(vv + bz[c])));
        } else {
          Hpre[o] = vv;
        }
      }
    }
}

// ---------------- GEMM2: 32x64 tiles, 2-wave blocks + final gate ----------------
__global__ __launch_bounds__(128) void k_gemm2(const short* __restrict__ rnH,
                                               const short* __restrict__ WT,
                                               const float* __restrict__ bh,
                                               const float* __restrict__ Hpre,
                                               const float* __restrict__ zb,
                                               const float* __restrict__ nodes,
                                               float* __restrict__ out) {
  __shared__ __align__(16) short As[32 * 72];
  __shared__ __align__(16) short Bs[64 * 72];
  int tid = threadIdx.x;
  int row0 = blockIdx.y * 32;           // [0,768)
  int col0 = blockIdx.x * 64;           // [0,512)
  int w = tid >> 6, l = tid & 63;
  int wc = w * 32;
  int ac0 = tid * 2;
  int ar0 = ac0 >> 3, ak0 = (ac0 & 7) * 8;
  int ar1 = (ac0 + 1) >> 3, ak1 = ((ac0 + 1) & 7) * 8;
  int bc0 = tid * 4;
  int br_ = bc0 >> 3, bk = (bc0 & 7) * 8;
  const short* ApA = rnH + (size_t)(row0 + ar0) * DD + ak0;
  const short* ApB = rnH + (size_t)(row0 + ar1) * DD + ak1;
  const short* Bp = WT + (size_t)2 * (512 * 1536) + (size_t)(col0 + br_) * 1536 + 1024 + bk;
  s8v a0 = *(const s8v*)ApA, a1 = *(const s8v*)ApB;
  s8v b0 = *(const s8v*)Bp, b1 = *(const s8v*)(Bp + 8);
  s8v b2 = *(const s8v*)(Bp + 16), b3 = *(const s8v*)(Bp + 24);
  f32x4 acc[2][2] = {};
  for (int k0 = 0; k0 < DD; k0 += 64) {
    *(s8v*)&As[ar0 * 72 + ak0] = a0;
    *(s8v*)&As[ar1 * 72 + ak1] = a1;
    *(s8v*)&Bs[br_ * 72 + bk] = b0;      *(s8v*)&Bs[br_ * 72 + bk + 8] = b1;
    *(s8v*)&Bs[br_ * 72 + bk + 16] = b2; *(s8v*)&Bs[br_ * 72 + bk + 24] = b3;
    __syncthreads();
    if (k0 + 64 < DD) {
      ApA += 64; ApB += 64; Bp += 64;
      a0 = *(const s8v*)ApA; a1 = *(const s8v*)ApB;
      b0 = *(const s8v*)Bp; b1 = *(const s8v*)(Bp + 8);
      b2 = *(const s8v*)(Bp + 16); b3 = *(const s8v*)(Bp + 24);
    }
    mfma_tile(As, Bs, 0, wc, l, acc);
    __syncthreads();
  }
  asm volatile("s_nop 7\n\ts_nop 7");
  int lr = l & 15, lg4 = (l >> 4) * 4;
#pragma unroll
  for (int fi = 0; fi < 2; ++fi)
#pragma unroll
    for (int fj = 0; fj < 2; ++fj) {
      f32x4 v = acc[fi][fj];
#pragma unroll
      for (int r = 0; r < 4; ++r) {
        int row = row0 + fi * 16 + lg4 + r;
        int c = col0 + wc + fj * 16 + lr;
        size_t o = (size_t)row * DD + c;
        float h = tanhf(v[r] + Hpre[o] + bh[c]);
        float zz = zb[o];
        float nd = nodes[o];
        out[o] = (1.f - zz) * nd + zz * h;
      }
    }
}

extern "C" void kernel_launch(void* const* d_in, const int* in_sizes, int n_in,
                              void* d_out, int out_size, void* d_ws, size_t ws_size,
                              hipStream_t stream) {
  const float* nodes = (const float*)d_in[0];
  const float* edges = (const float*)d_in[1];
  const int* adj_in = (const int*)d_in[2];
  const int* adj_out = (const int*)d_in[3];
  const void* exist_in = d_in[4];
  const void* exist_out = d_in[5];
  const float* Wa_in = (const float*)d_in[6];
  const float* ba_in = (const float*)d_in[7];
  const float* Wa_out = (const float*)d_in[8];
  const float* ba_out = (const float*)d_in[9];
  const float* Wr = (const float*)d_in[10];
  const float* br = (const float*)d_in[11];
  const float* Wz = (const float*)d_in[12];
  const float* bz = (const float*)d_in[13];
  const float* Wh = (const float*)d_in[14];
  const float* bh = (const float*)d_in[15];

  char* ws = (char*)d_ws;
  int* flags = (int*)ws;
  float* projp = (float*)(ws + WS_PROJP);
  short* nodesH = (short*)(ws + WS_NODESH);
  short* allmsgsH = (short*)(ws + WS_ALLMSGS);
  short* AcatH = (short*)(ws + WS_ACAT);
  short* edgesT = (short*)(ws + WS_EDGEST);
  short* WT = (short*)(ws + WS_WT);
  short* rnH = (short*)(ws + WS_RN);
  float* zb = (float*)(ws + WS_ZB);
  float* Hpre = (float*)(ws + WS_HPRE);
  float* out = (float*)d_out;

  k_prep<<<1102, 256, 0, stream>>>(edges, Wr, Wz, Wh, nodes, exist_in,
                                   exist_out, edgesT, WT, nodesH, AcatH, flags);
  k_gemm_msgs<<<dim3(64, 12), 256, 0, stream>>>(nodesH, edgesT, Wa_in, Wa_out,
                                                allmsgsH, projp);
  k_attn<<<2 * ROWS, 256, 0, stream>>>(allmsgsH, projp, adj_in, adj_out,
                                       exist_in, exist_out, flags, nodes,
                                       Wa_in, ba_in, Wa_out, ba_out, AcatH);
  k_gemm1<<<dim3(24, 24), 128, 0, stream>>>(AcatH, WT, br, bz, nodes, rnH, zb,
                                            Hpre);
  k_gemm2<<<dim3(8, 24), 128, 0, stream>>>(rnH, WT, bh, Hpre, zb, nodes, out);
}

// Round 14
// 60.337 us; speedup vs baseline: 1.0229x; 1.0229x over previous
//
#include <hip/hip_runtime.h>
#include <hip/hip_bf16.h>

// Problem dims (fixed by reference)
#define BB 8
#define NN 96
#define DD 512
#define EE 4
#define ROWS 768

typedef __attribute__((ext_vector_type(8))) short s8v;   // 8 bf16 = 4 VGPRs
typedef __attribute__((ext_vector_type(4))) short s4v;
typedef __attribute__((ext_vector_type(4))) float f32x4;

// ---------------- ws layout (flat; ws = 256 MiB) ----------------
#define WS_PROJP   4096                 // f32 [8][6144]       = 196,608
#define WS_NODESH  1048576              // bf16 [768][512]     = 786,432
#define WS_ALLMSGS 2097152              // bf16 [8*768][512]   = 6,291,456
#define WS_ACAT    8388608              // bf16 [768][1536]    = 2,359,296
#define WS_EDGEST  10747904             // bf16 [8][512][512]  = 4,194,304
#define WS_WT      14942208             // bf16 [3][512][1536] = 4,718,592
#define WS_RN      19660800             // bf16 [768][512]     = 786,432
#define WS_ZB      20447232             // f32  [768][512]     = 1,572,864
#define WS_HPRE    22020096             // f32  [768][512]     = 1,572,864

__device__ __forceinline__ short f2bf(float x) {   // RNE f32->bf16
  unsigned int u = __builtin_bit_cast(unsigned int, x);
  u += 0x7FFFu + ((u >> 16) & 1u);
  return (short)(u >> 16);
}
__device__ __forceinline__ float b2f(short s) {
  unsigned int u = ((unsigned int)(unsigned short)s) << 16;
  return __builtin_bit_cast(float, u);
}

__device__ __forceinline__ f32x4 mfma16(s8v a, s8v b, f32x4 c) {
  asm("v_mfma_f32_16x16x32_bf16 %0, %1, %2, %0" : "+v"(c) : "v"(a), "v"(b));
  return c;
}

__device__ __forceinline__ int get_exist(const void* p, int code, int idx) {
  switch (code) {
    case 0: return ((const unsigned char*)p)[idx] != 0;
    case 1: return ((const int*)p)[idx] != 0;
    case 2: return ((const float*)p)[idx] != 0.0f;
    default: return ((const long long*)p)[idx] != 0;
  }
}

// shared 64x64 f32->bf16 transpose tile (256 threads)
__device__ __forceinline__ void tr64(const float* __restrict__ src,
                                     short* __restrict__ dst, int dstPitch,
                                     int r0, int c0, float (*t)[65], int tt) {
  int row = tt >> 2, c16 = (tt & 3) * 16;
  const float* sp = src + (size_t)(r0 + row) * DD + c0 + c16;
#pragma unroll
  for (int i = 0; i < 4; ++i) {
    float4 v = *(const float4*)(sp + i * 4);
    t[row][c16 + i * 4 + 0] = v.x; t[row][c16 + i * 4 + 1] = v.y;
    t[row][c16 + i * 4 + 2] = v.z; t[row][c16 + i * 4 + 3] = v.w;
  }
  __syncthreads();
  short* dp = dst + (size_t)(c0 + row) * dstPitch + r0 + c16;
#pragma unroll
  for (int i = 0; i < 4; ++i) {
    s4v o;
    o[0] = f2bf(t[c16 + i * 4 + 0][row]);
    o[1] = f2bf(t[c16 + i * 4 + 1][row]);
    o[2] = f2bf(t[c16 + i * 4 + 2][row]);
    o[3] = f2bf(t[c16 + i * 4 + 3][row]);
    *(s4v*)(dp + i * 4) = o;
  }
}

// ---------------- prep: 562 blocks — edgesT (0..511), nodesH (512..559), detect ----------------
__global__ __launch_bounds__(256) void k_prep(const float* __restrict__ edges,
                                              const float* __restrict__ nodes,
                                              const void* exist_in,
                                              const void* exist_out,
                                              short* __restrict__ edgesT,
                                              short* __restrict__ nodesH,
                                              short* __restrict__ AcatH,
                                              int* __restrict__ flags) {
  __shared__ float t[64][65];
  __shared__ int red[3];
  int task = blockIdx.x;
  int tt = threadIdx.x;
  if (task < 512) {
    int e = task >> 6, rem = task & 63;
    tr64(edges + (size_t)e * DD * DD, edgesT + (size_t)e * DD * DD, DD,
         (rem >> 3) * 64, (rem & 7) * 64, t, tt);
  } else if (task < 560) {
    int r0 = (task - 512) * 16;
    int c4 = (tt & 127) * 4;
#pragma unroll
    for (int p2 = 0; p2 < 8; ++p2) {
      int row = r0 + p2 * 2 + (tt >> 7);
      float4 v = *(const float4*)(nodes + (size_t)row * DD + c4);
      s4v o;
      o[0] = f2bf(v.x); o[1] = f2bf(v.y); o[2] = f2bf(v.z); o[3] = f2bf(v.w);
      *(s4v*)(nodesH + (size_t)row * DD + c4) = o;
      *(s4v*)(AcatH + (size_t)row * 1536 + 1024 + c4) = o;
    }
  } else {
    int y = task - 560;
    if (tt < 3) red[tt] = 0;
    __syncthreads();
    const uint4* p = (const uint4*)(y ? exist_out : exist_in);
    int mis = 0, gt = 0, od = 0;
    for (int i = tt; i < 4608; i += 256) {    // first 73728 bytes
      uint4 v = p[i];
      unsigned any = v.x | v.y | v.z | v.w;
      if (any) {
        if (any & 0xFFFFFF00u) mis = 1;
        if (any & 0xFEFEFEFEu) gt = 1;
        if (v.y | v.w) od = 1;
      }
    }
    if (mis) atomicOr(&red[0], 1);
    if (gt) atomicOr(&red[1], 1);
    if (od) atomicOr(&red[2], 1);
    __syncthreads();
    if (tt == 0) flags[y] = red[0] ? (red[1] ? 2 : 0) : (red[2] ? 1 : 3);
  }
}

// ---------------- MFMA tile helper (R6/R9 proven) ----------------
__device__ __forceinline__ void mfma_tile(const short* As, const short* Bs,
                                          int wr, int wc, int l, f32x4 acc[2][2]) {
  int lr = l & 15, lg = l >> 4;
#pragma unroll
  for (int ks = 0; ks < 64; ks += 32) {
    s8v a0 = *(const s8v*)&As[(wr + lr) * 72 + ks + 8 * lg];
    s8v a1 = *(const s8v*)&As[(wr + 16 + lr) * 72 + ks + 8 * lg];
    s8v b0 = *(const s8v*)&Bs[(wc + lr) * 72 + ks + 8 * lg];
    s8v b1 = *(const s8v*)&Bs[(wc + 16 + lr) * 72 + ks + 8 * lg];
    acc[0][0] = mfma16(a0, b0, acc[0][0]);
    acc[0][1] = mfma16(a0, b1, acc[0][1]);
    acc[1][0] = mfma16(a1, b0, acc[1][0]);
    acc[1][1] = mfma16(a1, b1, acc[1][1]);
  }
}

// ---------------- GEMM msgs (pipelined, R9 proven) + fused proj partials ----------------
__global__ __launch_bounds__(256) void k_gemm_msgs(const short* __restrict__ nodesH,
                                                   const short* __restrict__ edgesT,
                                                   const float* __restrict__ Wa_in,
                                                   const float* __restrict__ Wa_out,
                                                   short* __restrict__ C,
                                                   float* __restrict__ projp) {
  __shared__ __align__(16) short As[64 * 72];
  __shared__ __align__(16) short Bs[64 * 72];
  __shared__ float pp[128];
  int tid = threadIdx.x;
  int row0 = blockIdx.y * 64;
  int col0 = blockIdx.x * 64;        // [0,4096)
  int de = col0 >> 9, h0 = col0 & 511;
  int w = tid >> 6, l = tid & 63;
  int wr = (w >> 1) * 32, wc = (w & 1) * 32;
  int srow = tid >> 2, scc = (tid & 3) * 16;
  const short* Ap = nodesH + (size_t)(row0 + srow) * DD + scc;
  const short* Bp = edgesT + (size_t)de * DD * DD + (size_t)(h0 + srow) * DD + scc;
  s8v a0 = *(const s8v*)Ap, a1 = *(const s8v*)(Ap + 8);
  s8v b0 = *(const s8v*)Bp, b1 = *(const s8v*)(Bp + 8);
  f32x4 acc[2][2] = {};
  for (int k0 = 0; k0 < DD; k0 += 64) {
    *(s8v*)&As[srow * 72 + scc] = a0; *(s8v*)&As[srow * 72 + scc + 8] = a1;
    *(s8v*)&Bs[srow * 72 + scc] = b0; *(s8v*)&Bs[srow * 72 + scc + 8] = b1;
    __syncthreads();
    if (k0 + 64 < DD) {        // prefetch next K-tile into regs (overlaps MFMA)
      Ap += 64; Bp += 64;
      a0 = *(const s8v*)Ap; a1 = *(const s8v*)(Ap + 8);
      b0 = *(const s8v*)Bp; b1 = *(const s8v*)(Bp + 8);
    }
    mfma_tile(As, Bs, wr, wc, l, acc);
    __syncthreads();
  }
  asm volatile("s_nop 7\n\ts_nop 7");   // MFMA->VALU writeback hazard guard
  int lr = l & 15, lg4 = (l >> 4) * 4;
#pragma unroll
  for (int fi = 0; fi < 2; ++fi)
#pragma unroll
    for (int fj = 0; fj < 2; ++fj) {
      f32x4 v = acc[fi][fj];
#pragma unroll
      for (int r = 0; r < 4; ++r) {
        int row = row0 + wr + fi * 16 + lg4 + r;
        int col = h0 + wc + fj * 16 + lr;
        C[((size_t)(de * ROWS + row)) * DD + col] = f2bf(v[r]);
      }
    }
  // ---- fused proj partial ----
  const float* wa2 = ((de >> 2) ? Wa_out : Wa_in) + DD;
  float w0 = wa2[h0 + wc + lr];
  float w1 = wa2[h0 + wc + 16 + lr];
  float pr[2][4];
#pragma unroll
  for (int fi = 0; fi < 2; ++fi)
#pragma unroll
    for (int r = 0; r < 4; ++r)
      pr[fi][r] = acc[fi][0][r] * w0 + acc[fi][1][r] * w1;
#pragma unroll
  for (int off = 1; off < 16; off <<= 1)
#pragma unroll
    for (int fi = 0; fi < 2; ++fi)
#pragma unroll
      for (int r = 0; r < 4; ++r) pr[fi][r] += __shfl_xor(pr[fi][r], off);
  if (lr == 0) {
#pragma unroll
    for (int fi = 0; fi < 2; ++fi)
#pragma unroll
      for (int r = 0; r < 4; ++r)
        pp[(w & 1) * 64 + wr + fi * 16 + lg4 + r] = pr[fi][r];
  }
  __syncthreads();
  if (tid < 64)
    projp[(size_t)(blockIdx.x & 7) * 6144 + de * ROWS + row0 + tid] =
        pp[tid] + pp[64 + tid];
}

// ---------------- attention (R9 proven) + co-scheduled WT transposes ----------------
__global__ __launch_bounds__(256) void k_attn(const short* __restrict__ allmsgsH,
                                              const float* __restrict__ projp,
                                              const int* __restrict__ adj_in,
                                              const int* __restrict__ adj_out,
                                              const void* exist_in,
                                              const void* exist_out,
                                              const int* __restrict__ fr,
                                              const float* __restrict__ nodes,
                                              const float* __restrict__ Wa_in,
                                              const float* __restrict__ ba_in,
                                              const float* __restrict__ Wa_out,
                                              const float* __restrict__ ba_out,
                                              const float* __restrict__ Wr,
                                              const float* __restrict__ Wz,
                                              const float* __restrict__ Wh,
                                              short* __restrict__ WT,
                                              short* __restrict__ AcatH) {
  __shared__ float trb[64][65];
  __shared__ float s_w[NN];
  __shared__ int s_off[NN];
  __shared__ int s_list[NN];
  __shared__ int s_cnt[2];
  __shared__ float s_part[5];
  int blk = blockIdx.x;
  int t = threadIdx.x;
  if (blk >= 1536) {            // ---- WT transpose tiles (for gemm1/gemm2) ----
    int q = blk - 1536;
    int z = q / 192, rem = q % 192;
    const float* src = z == 0 ? Wr : (z == 1 ? Wz : Wh);
    tr64(src, WT + (size_t)z * (512 * 1536), 1536, (rem >> 3) * 64,
         (rem & 7) * 64, trb, t);
    return;
  }
  int dir = blk / ROWS;
  int row = blk % ROWS;
  int b = row / NN;
  const int* adj = dir ? adj_out : adj_in;
  const void* ex = dir ? exist_out : exist_in;
  int code = fr[dir];
  int wv = t >> 6, lane = t & 63;
  const float* wa = dir ? Wa_out : Wa_in;
  float2 nv = *(const float2*)(nodes + (size_t)row * DD + 2 * t);
  float p = fmaf(nv.x, wa[2 * t], nv.y * wa[2 * t + 1]);
#pragma unroll
  for (int off = 32; off; off >>= 1) p += __shfl_xor(p, off);
  if (lane == 0) s_part[wv] = p;
  int ex_ = 0, tj_ = 0;
  if (t < NN) {
    int idx = row * NN + t;
    ex_ = get_exist(ex, code, idx);
    tj_ = adj[idx];
    s_off[t] = ((dir * 4 + tj_) * ROWS + b * NN + t) * DD;
  }
  if (wv == 0) {
    unsigned long long m = __ballot(ex_);
    int pos = __popcll(m & ((1ull << lane) - 1));
    if (ex_) s_list[pos] = t;
    if (lane == 0) s_cnt[0] = (int)__popcll(m);
  } else if (wv == 1) {
    unsigned long long m = __ballot(t < NN && ex_);
    int pos = __popcll(m & ((1ull << lane) - 1));
    if (t < NN && ex_) s_list[64 + pos] = t;
    if (lane == 0) s_cnt[1] = (int)__popcll(m);
  }
  __syncthreads();
  float s1v = s_part[0] + s_part[1] + s_part[2] + s_part[3] +
              (dir ? ba_out[0] : ba_in[0]);
  if (t < NN) {
    float sc = -1e9f;
    if (ex_) {
      size_t base = (size_t)(dir * 4 + tj_) * ROWS + b * NN + t;
      float pv = 0.f;
#pragma unroll
      for (int c = 0; c < 8; ++c) pv += projp[(size_t)c * 6144 + base];
      float x = s1v + pv;
      sc = x >= 0.f ? x : 0.2f * x;
    }
    s_w[t] = sc;
  }
  __syncthreads();
  if (t < 64) {
    float e1 = s_w[t];
    float e2 = (t < 32) ? s_w[t + 64] : -1e30f;
    float mx = fmaxf(e1, e2);
#pragma unroll
    for (int off = 32; off; off >>= 1) mx = fmaxf(mx, __shfl_xor(mx, off));
    float w1 = (e1 > -1e8f) ? __expf(e1 - mx) : 0.f;
    float w2 = (t < 32 && e2 > -1e8f) ? __expf(e2 - mx) : 0.f;
    s_w[t] = w1;
    if (t < 32) s_w[t + 64] = w2;
    float sm = w1 + w2;
#pragma unroll
    for (int off = 32; off; off >>= 1) sm += __shfl_xor(sm, off);
    if (t == 0) s_part[4] = 1.f / sm;
  }
  __syncthreads();
  float inv = s_part[4];
  int c0 = s_cnt[0], c1 = s_cnt[1];
  float acc0 = 0.f, acc1 = 0.f;
  int t2 = 2 * t;
#pragma unroll 4
  for (int q = 0; q < c0; ++q) {
    int j = s_list[q];
    float wj = s_w[j];
    unsigned u = *(const unsigned*)(allmsgsH + s_off[j] + t2);
    acc0 = fmaf(wj, b2f((short)(u & 0xFFFF)), acc0);
    acc1 = fmaf(wj, b2f((short)(u >> 16)), acc1);
  }
#pragma unroll 4
  for (int q = 0; q < c1; ++q) {
    int j = s_list[64 + q];
    float wj = s_w[j];
    unsigned u = *(const unsigned*)(allmsgsH + s_off[j] + t2);
    acc0 = fmaf(wj, b2f((short)(u & 0xFFFF)), acc0);
    acc1 = fmaf(wj, b2f((short)(u >> 16)), acc1);
  }
  unsigned o0 = (unsigned short)f2bf(acc0 * inv);
  unsigned o1 = (unsigned short)f2bf(acc1 * inv);
  *(unsigned*)(AcatH + (size_t)row * 1536 + dir * DD + t2) = o0 | (o1 << 16);
}

// ---------------- GEMM1 (pipelined, R9/R12 proven): AcatH @ {WrT|WzT|WhT[:,:1024]} ----------------
__global__ __launch_bounds__(256) void k_gemm1(const short* __restrict__ AcatH,
                                               const short* __restrict__ WT,
                                               const float* __restrict__ br,
                                               const float* __restrict__ bz,
                                               const float* __restrict__ nodes,
                                               short* __restrict__ rnH,
                                               float* __restrict__ zb,
                                               float* __restrict__ Hpre) {
  __shared__ __align__(16) short As[64 * 72];
  __shared__ __align__(16) short Bs[64 * 72];
  int tid = threadIdx.x;
  int row0 = blockIdx.y * 64;
  int col0 = blockIdx.x * 64;           // [0,1536)
  int region = col0 >> 9, c0 = col0 & 511;
  int K = (region == 2) ? 1024 : 1536;
  int w = tid >> 6, l = tid & 63;
  int wr = (w >> 1) * 32, wc = (w & 1) * 32;
  int srow = tid >> 2, scc = (tid & 3) * 16;
  const short* Ap = AcatH + (size_t)(row0 + srow) * 1536 + scc;
  const short* Bp = WT + (size_t)region * (512 * 1536) + (size_t)(c0 + srow) * 1536 + scc;
  s8v a0 = *(const s8v*)Ap, a1 = *(const s8v*)(Ap + 8);
  s8v b0 = *(const s8v*)Bp, b1 = *(const s8v*)(Bp + 8);
  f32x4 acc[2][2] = {};
  for (int k0 = 0; k0 < K; k0 += 64) {
    *(s8v*)&As[srow * 72 + scc] = a0; *(s8v*)&As[srow * 72 + scc + 8] = a1;
    *(s8v*)&Bs[srow * 72 + scc] = b0; *(s8v*)&Bs[srow * 72 + scc + 8] = b1;
    __syncthreads();
    if (k0 + 64 < K) {
      Ap += 64; Bp += 64;
      a0 = *(const s8v*)Ap; a1 = *(const s8v*)(Ap + 8);
      b0 = *(const s8v*)Bp; b1 = *(const s8v*)(Bp + 8);
    }
    mfma_tile(As, Bs, wr, wc, l, acc);
    __syncthreads();
  }
  asm volatile("s_nop 7\n\ts_nop 7");
  int lr = l & 15, lg4 = (l >> 4) * 4;
#pragma unroll
  for (int fi = 0; fi < 2; ++fi)
#pragma unroll
    for (int fj = 0; fj < 2; ++fj) {
      f32x4 v = acc[fi][fj];
#pragma unroll
      for (int r = 0; r < 4; ++r) {
        int row = row0 + wr + fi * 16 + lg4 + r;
        int c = c0 + wc + fj * 16 + lr;
        float vv = v[r];
        size_t o = (size_t)row * DD + c;
        if (region == 0) {
          float s = 1.f / (1.f + __expf(-(vv + br[c])));
          rnH[o] = f2bf(s * nodes[o]);
        } else if (region == 1) {
          zb[o] = 1.f / (1.f + __expf(-(vv + bz[c])));
        } else {
          Hpre[o] = vv;
        }
      }
    }
}

// ---------------- GEMM2 (pipelined, R9/R12 proven): rn @ WhT[:,1024:] + final gate ----------------
__global__ __launch_bounds__(256) void k_gemm2(const short* __restrict__ rnH,
                                               const short* __restrict__ WT,
                                               const float* __restrict__ bh,
                                               const float* __restrict__ Hpre,
                                               const float* __restrict__ zb,
                                               const float* __restrict__ nodes,
                                               float* __restrict__ out) {
  __shared__ __align__(16) short As[64 * 72];
  __shared__ __align__(16) short Bs[64 * 72];
  int tid = threadIdx.x;
  int row0 = blockIdx.y * 64;
  int col0 = blockIdx.x * 64;           // [0,512)
  int w = tid >> 6, l = tid & 63;
  int wr = (w >> 1) * 32, wc = (w & 1) * 32;
  int srow = tid >> 2, scc = (tid & 3) * 16;
  const short* Ap = rnH + (size_t)(row0 + srow) * DD + scc;
  const short* Bp = WT + (size_t)2 * (512 * 1536) + (size_t)(col0 + srow) * 1536 + 1024 + scc;
  s8v a0 = *(const s8v*)Ap, a1 = *(const s8v*)(Ap + 8);
  s8v b0 = *(const s8v*)Bp, b1 = *(const s8v*)(Bp + 8);
  f32x4 acc[2][2] = {};
  for (int k0 = 0; k0 < DD; k0 += 64) {
    *(s8v*)&As[srow * 72 + scc] = a0; *(s8v*)&As[srow * 72 + scc + 8] = a1;
    *(s8v*)&Bs[srow * 72 + scc] = b0; *(s8v*)&Bs[srow * 72 + scc + 8] = b1;
    __syncthreads();
    if (k0 + 64 < DD) {
      Ap += 64; Bp += 64;
      a0 = *(const s8v*)Ap; a1 = *(const s8v*)(Ap + 8);
      b0 = *(const s8v*)Bp; b1 = *(const s8v*)(Bp + 8);
    }
    mfma_tile(As, Bs, wr, wc, l, acc);
    __syncthreads();
  }
  asm volatile("s_nop 7\n\ts_nop 7");
  int lr = l & 15, lg4 = (l >> 4) * 4;
#pragma unroll
  for (int fi = 0; fi < 2; ++fi)
#pragma unroll
    for (int fj = 0; fj < 2; ++fj) {
      f32x4 v = acc[fi][fj];
#pragma unroll
      for (int r = 0; r < 4; ++r) {
        int row = row0 + wr + fi * 16 + lg4 + r;
        int c = col0 + wc + fj * 16 + lr;
        size_t o = (size_t)row * DD + c;
        float h = tanhf(v[r] + Hpre[o] + bh[c]);
        float zz = zb[o];
        float nd = nodes[o];
        out[o] = (1.f - zz) * nd + zz * h;
      }
    }
}

extern "C" void kernel_launch(void* const* d_in, const int* in_sizes, int n_in,
                              void* d_out, int out_size, void* d_ws, size_t ws_size,
                              hipStream_t stream) {
  const float* nodes = (const float*)d_in[0];
  const float* edges = (const float*)d_in[1];
  const int* adj_in = (const int*)d_in[2];
  const int* adj_out = (const int*)d_in[3];
  const void* exist_in = d_in[4];
  const void* exist_out = d_in[5];
  const float* Wa_in = (const float*)d_in[6];
  const float* ba_in = (const float*)d_in[7];
  const float* Wa_out = (const float*)d_in[8];
  const float* ba_out = (const float*)d_in[9];
  const float* Wr = (const float*)d_in[10];
  const float* br = (const float*)d_in[11];
  const float* Wz = (const float*)d_in[12];
  const float* bz = (const float*)d_in[13];
  const float* Wh = (const float*)d_in[14];
  const float* bh = (const float*)d_in[15];

  char* ws = (char*)d_ws;
  int* flags = (int*)ws;
  float* projp = (float*)(ws + WS_PROJP);
  short* nodesH = (short*)(ws + WS_NODESH);
  short* allmsgsH = (short*)(ws + WS_ALLMSGS);
  short* AcatH = (short*)(ws + WS_ACAT);
  short* edgesT = (short*)(ws + WS_EDGEST);
  short* WT = (short*)(ws + WS_WT);
  short* rnH = (short*)(ws + WS_RN);
  float* zb = (float*)(ws + WS_ZB);
  float* Hpre = (float*)(ws + WS_HPRE);
  float* out = (float*)d_out;

  k_prep<<<562, 256, 0, stream>>>(edges, nodes, exist_in, exist_out, edgesT,
                                  nodesH, AcatH, flags);
  k_gemm_msgs<<<dim3(64, 12), 256, 0, stream>>>(nodesH, edgesT, Wa_in, Wa_out,
                                                allmsgsH, projp);
  k_attn<<<1536 + 576, 256, 0, stream>>>(allmsgsH, projp, adj_in, adj_out,
                                         exist_in, exist_out, flags, nodes,
                                         Wa_in, ba_in, Wa_out, ba_out, Wr, Wz,
                                         Wh, WT, AcatH);
  k_gemm1<<<dim3(24, 12), 256, 0, stream>>>(AcatH, WT, br, bz, nodes, rnH, zb,
                                            Hpre);
  k_gemm2<<<dim3(8, 12), 256, 0, stream>>>(rnH, WT, bh, Hpre, zb, nodes, out);
}